// Round 1
// baseline (576.539 us; speedup 1.0000x reference)
//
#include <hip/hip_runtime.h>
#include <cstdint>
#include <cstddef>

// Problem constants
#define NTOK 2048      // B*S
#define DDIM 1024
#define FDIM 2048
#define NEXP 14
#define MAXT 2048      // max tokens per expert (one slot each)

typedef __attribute__((ext_vector_type(8))) short short8;
typedef __attribute__((ext_vector_type(4))) float floatx4;

__device__ __forceinline__ unsigned short f2bf(float f) {
    unsigned u = __float_as_uint(f);
    unsigned r = u + 0x7fffu + ((u >> 16) & 1u);   // RNE
    return (unsigned short)(r >> 16);
}

// ---------------- zero counters ----------------
__global__ void zero_cnt_kernel(int* __restrict__ cnt) {
    if (threadIdx.x < NEXP) cnt[threadIdx.x] = 0;
}

// ---------------- gating: one wave per token ----------------
__global__ __launch_bounds__(256) void gate_kernel(
    const float* __restrict__ x, const float* __restrict__ gw,
    int* __restrict__ cnt, int* __restrict__ lists, float* __restrict__ wt)
{
    const int wave = threadIdx.x >> 6, lane = threadIdx.x & 63;
    const int n = blockIdx.x * 4 + wave;
    float part[NEXP];
#pragma unroll
    for (int e = 0; e < NEXP; ++e) part[e] = 0.f;
    const float* xr = x + (size_t)n * DDIM;
#pragma unroll 4
    for (int kk = 0; kk < DDIM / 64; ++kk) {
        const int d = kk * 64 + lane;
        const float xv = xr[d];
#pragma unroll
        for (int e = 0; e < NEXP; ++e)
            part[e] = fmaf(xv, gw[e * DDIM + d], part[e]);
    }
#pragma unroll
    for (int e = 0; e < NEXP; ++e) {
        float v = part[e];
        for (int off = 32; off; off >>= 1) v += __shfl_xor(v, off);
        part[e] = v;
    }
    // all lanes hold identical logits now
    int i0 = 0; float l0 = part[0];
#pragma unroll
    for (int e = 1; e < NEXP; ++e) if (part[e] > l0) { l0 = part[e]; i0 = e; }
    int i1 = -1; float l1 = -3.0e38f;
#pragma unroll
    for (int e = 0; e < NEXP; ++e) if (e != i0 && part[e] > l1) { l1 = part[e]; i1 = e; }
    if (lane == 0) {
        const float r  = __expf(l1 - l0);
        const float w0 = 1.f / (1.f + r);
        const float w1v = r / (1.f + r);
        wt[2 * n]     = w0;
        wt[2 * n + 1] = w1v;
        int p0 = atomicAdd(&cnt[i0], 1); lists[i0 * MAXT + p0] = 2 * n;
        int p1 = atomicAdd(&cnt[i1], 1); lists[i1 * MAXT + p1] = 2 * n + 1;
    }
}

// ---------------- GEMM1: hh[p][F] = gelu(x[tok] @ w1[e] + b1[e]) ----------------
// 128x128 tile, K-chunk 32, 4 waves, each wave 64x64 via 4x4 mfma_f32_16x16x32_bf16
#define LDSTR 40   // LDS row stride in bf16 elems (80 B -> 20-bank stride, ~2-way max)

__global__ __launch_bounds__(256) void gemm1_kernel(
    const float* __restrict__ x, const float* __restrict__ w1,
    const float* __restrict__ b1, const int* __restrict__ cnt,
    const int* __restrict__ lists, unsigned short* __restrict__ hh)
{
    const int e = blockIdx.z, mt = blockIdx.y, nt = blockIdx.x;
    const int count = cnt[e];
    if (mt * 128 >= count) return;
    const int* list = lists + e * MAXT + mt * 128;
    const int mloc = min(128, count - mt * 128);

    __shared__ __align__(16) unsigned short As[128 * LDSTR];
    __shared__ __align__(16) unsigned short Bs[128 * LDSTR];

    const int t = threadIdx.x;
    const int lane = t & 63, wave = t >> 6;
    const int wm = (wave >> 1) * 64, wn = (wave & 1) * 64;
    const int lrow = lane & 15, lquad = lane >> 4;

    // A staging: 2 threads/row, 16 cols each
    const int arow = t >> 1, ahalf = (t & 1) * 16;
    const int tokA = list[arow < mloc ? arow : 0] >> 1;
    const float* aSrc = x + (size_t)tokA * DDIM + ahalf;
    // B staging: thread -> (k = t>>3, 16 n's at bq)
    const int bk = t >> 3, bq = (t & 7) * 16;
    const float* bSrc = w1 + (size_t)e * DDIM * FDIM + (size_t)bk * FDIM + nt * 128 + bq;

    floatx4 acc[4][4];
#pragma unroll
    for (int i = 0; i < 4; ++i)
#pragma unroll
        for (int j = 0; j < 4; ++j) acc[i][j] = (floatx4)0.f;

    for (int k0 = 0; k0 < DDIM; k0 += 32) {
        // stage A (fp32 -> bf16), row-major [row][k]
        {
            const float4* ap = (const float4*)(aSrc + k0);
            float4 a0 = ap[0], a1 = ap[1], a2 = ap[2], a3 = ap[3];
            union { short8 v; unsigned short s[8]; } p0, p1;
            p0.s[0]=f2bf(a0.x); p0.s[1]=f2bf(a0.y); p0.s[2]=f2bf(a0.z); p0.s[3]=f2bf(a0.w);
            p0.s[4]=f2bf(a1.x); p0.s[5]=f2bf(a1.y); p0.s[6]=f2bf(a1.z); p0.s[7]=f2bf(a1.w);
            p1.s[0]=f2bf(a2.x); p1.s[1]=f2bf(a2.y); p1.s[2]=f2bf(a2.z); p1.s[3]=f2bf(a2.w);
            p1.s[4]=f2bf(a3.x); p1.s[5]=f2bf(a3.y); p1.s[6]=f2bf(a3.z); p1.s[7]=f2bf(a3.w);
            *(short8*)(As + arow * LDSTR + ahalf)     = p0.v;
            *(short8*)(As + arow * LDSTR + ahalf + 8) = p1.v;
        }
        // stage B transposed: Bs[n][k]
        {
            const float4* bp = (const float4*)(bSrc + (size_t)k0 * FDIM);
            float4 b0 = bp[0], b1v = bp[1], b2v = bp[2], b3v = bp[3];
            float vals[16] = { b0.x,b0.y,b0.z,b0.w, b1v.x,b1v.y,b1v.z,b1v.w,
                               b2v.x,b2v.y,b2v.z,b2v.w, b3v.x,b3v.y,b3v.z,b3v.w };
#pragma unroll
            for (int j = 0; j < 16; ++j)
                Bs[(bq + j) * LDSTR + bk] = f2bf(vals[j]);
        }
        __syncthreads();
        short8 af[4], bfg[4];
#pragma unroll
        for (int i = 0; i < 4; ++i)
            af[i] = *(const short8*)(As + (wm + i * 16 + lrow) * LDSTR + lquad * 8);
#pragma unroll
        for (int j = 0; j < 4; ++j)
            bfg[j] = *(const short8*)(Bs + (wn + j * 16 + lrow) * LDSTR + lquad * 8);
#pragma unroll
        for (int i = 0; i < 4; ++i)
#pragma unroll
            for (int j = 0; j < 4; ++j)
                acc[i][j] = __builtin_amdgcn_mfma_f32_16x16x32_bf16(af[i], bfg[j], acc[i][j], 0, 0, 0);
        __syncthreads();
    }
    // epilogue: bias + exact gelu, scatter rows to hh[pair][F]
#pragma unroll
    for (int j = 0; j < 4; ++j) {
        const int n = nt * 128 + wn + j * 16 + lrow;
        const float bias = b1[e * FDIM + n];
#pragma unroll
        for (int i = 0; i < 4; ++i) {
            const int mbase = wm + i * 16 + lquad * 4;
#pragma unroll
            for (int r = 0; r < 4; ++r) {
                const int m = mbase + r;
                if (m < mloc) {
                    const int p = list[m];
                    float v = acc[i][j][r] + bias;
                    v = 0.5f * v * (1.0f + erff(v * 0.70710678118654752f));
                    hh[(size_t)p * FDIM + n] = f2bf(v);
                }
            }
        }
    }
}

// ---------------- GEMM2: out_s[tok][D] = wt[p] * (hh[p] @ w2[e] + b2[e]) ----------------
__global__ __launch_bounds__(256) void gemm2_kernel(
    const unsigned short* __restrict__ hh, const float* __restrict__ w2,
    const float* __restrict__ b2, const int* __restrict__ cnt,
    const int* __restrict__ lists, const float* __restrict__ wt,
    float* __restrict__ out0, float* __restrict__ out1)
{
    const int e = blockIdx.z, mt = blockIdx.y, nt = blockIdx.x;
    const int count = cnt[e];
    if (mt * 128 >= count) return;
    const int* list = lists + e * MAXT + mt * 128;
    const int mloc = min(128, count - mt * 128);

    __shared__ __align__(16) unsigned short As[128 * LDSTR];
    __shared__ __align__(16) unsigned short Bs[128 * LDSTR];

    const int t = threadIdx.x;
    const int lane = t & 63, wave = t >> 6;
    const int wm = (wave >> 1) * 64, wn = (wave & 1) * 64;
    const int lrow = lane & 15, lquad = lane >> 4;

    const int arow = t >> 1, ahalf = (t & 1) * 16;
    const int pA = list[arow < mloc ? arow : 0];
    const unsigned short* aSrc = hh + (size_t)pA * FDIM + ahalf;
    const int bk = t >> 3, bq = (t & 7) * 16;
    const float* bSrc = w2 + (size_t)e * FDIM * DDIM + (size_t)bk * DDIM + nt * 128 + bq;

    floatx4 acc[4][4];
#pragma unroll
    for (int i = 0; i < 4; ++i)
#pragma unroll
        for (int j = 0; j < 4; ++j) acc[i][j] = (floatx4)0.f;

    for (int k0 = 0; k0 < FDIM; k0 += 32) {
        // stage A (already bf16)
        {
            short8 h0 = *(const short8*)(aSrc + k0);
            short8 h1 = *(const short8*)(aSrc + k0 + 8);
            *(short8*)(As + arow * LDSTR + ahalf)     = h0;
            *(short8*)(As + arow * LDSTR + ahalf + 8) = h1;
        }
        // stage B transposed
        {
            const float4* bp = (const float4*)(bSrc + (size_t)k0 * DDIM);
            float4 b0 = bp[0], b1v = bp[1], b2v = bp[2], b3v = bp[3];
            float vals[16] = { b0.x,b0.y,b0.z,b0.w, b1v.x,b1v.y,b1v.z,b1v.w,
                               b2v.x,b2v.y,b2v.z,b2v.w, b3v.x,b3v.y,b3v.z,b3v.w };
#pragma unroll
            for (int j = 0; j < 16; ++j)
                Bs[(bq + j) * LDSTR + bk] = f2bf(vals[j]);
        }
        __syncthreads();
        short8 af[4], bfg[4];
#pragma unroll
        for (int i = 0; i < 4; ++i)
            af[i] = *(const short8*)(As + (wm + i * 16 + lrow) * LDSTR + lquad * 8);
#pragma unroll
        for (int j = 0; j < 4; ++j)
            bfg[j] = *(const short8*)(Bs + (wn + j * 16 + lrow) * LDSTR + lquad * 8);
#pragma unroll
        for (int i = 0; i < 4; ++i)
#pragma unroll
            for (int j = 0; j < 4; ++j)
                acc[i][j] = __builtin_amdgcn_mfma_f32_16x16x32_bf16(af[i], bfg[j], acc[i][j], 0, 0, 0);
        __syncthreads();
    }
#pragma unroll
    for (int j = 0; j < 4; ++j) {
        const int n = nt * 128 + wn + j * 16 + lrow;
        const float bias = b2[e * DDIM + n];
#pragma unroll
        for (int i = 0; i < 4; ++i) {
            const int mbase = wm + i * 16 + lquad * 4;
#pragma unroll
            for (int r = 0; r < 4; ++r) {
                const int m = mbase + r;
                if (m < mloc) {
                    const int p = list[m];
                    const int tok = p >> 1;
                    float v = (acc[i][j][r] + bias) * wt[p];
                    float* dst = (p & 1) ? out1 : out0;
                    dst[(size_t)tok * DDIM + n] = v;
                }
            }
        }
    }
}

// ---------------- finalize: out = clip(x + out0 + out1) ----------------
__global__ __launch_bounds__(256) void finalize_kernel(
    const float* __restrict__ x, const float* __restrict__ o1,
    float* __restrict__ out)   // out currently holds out0
{
    const size_t i = ((size_t)blockIdx.x * 256 + threadIdx.x) * 4;
    float4 xv = *(const float4*)(x + i);
    float4 a  = *(const float4*)(out + i);
    float4 b  = *(const float4*)(o1 + i);
    float4 r;
    r.x = fminf(fmaxf(xv.x + a.x + b.x, -100.f), 100.f);
    r.y = fminf(fmaxf(xv.y + a.y + b.y, -100.f), 100.f);
    r.z = fminf(fmaxf(xv.z + a.z + b.z, -100.f), 100.f);
    r.w = fminf(fmaxf(xv.w + a.w + b.w, -100.f), 100.f);
    *(float4*)(out + i) = r;
}

extern "C" void kernel_launch(void* const* d_in, const int* in_sizes, int n_in,
                              void* d_out, int out_size, void* d_ws, size_t ws_size,
                              hipStream_t stream) {
    const float* h  = (const float*)d_in[0];
    const float* gw = (const float*)d_in[1];
    const float* w1 = (const float*)d_in[2];
    const float* b1 = (const float*)d_in[3];
    const float* w2 = (const float*)d_in[4];
    const float* b2 = (const float*)d_in[5];
    float* out = (float*)d_out;

    // workspace layout
    char* ws = (char*)d_ws;
    int*   cnt   = (int*)ws;                                   // 56 B (reserve 256)
    int*   lists = (int*)(ws + 256);                           // 14*2048*4 = 114688
    float* wt    = (float*)(ws + 256 + 114688);                // 4096*4   = 16384
    float* o1    = (float*)(ws + 131584);                      // 2048*1024*4 = 8388608
    unsigned short* hh = (unsigned short*)(ws + 131584 + 8388608); // 4096*2048*2 = 16777216
    // total ws use: ~25.3 MB

    zero_cnt_kernel<<<1, 64, 0, stream>>>(cnt);
    gate_kernel<<<NTOK / 4, 256, 0, stream>>>(h, gw, cnt, lists, wt);
    gemm1_kernel<<<dim3(FDIM / 128, MAXT / 128, NEXP), 256, 0, stream>>>(h, w1, b1, cnt, lists, hh);
    gemm2_kernel<<<dim3(DDIM / 128, MAXT / 128, NEXP), 256, 0, stream>>>(hh, w2, b2, cnt, lists, wt, out, o1);
    finalize_kernel<<<NTOK * DDIM / (256 * 4), 256, 0, stream>>>(h, o1, out);
}

// Round 2
// 496.109 us; speedup vs baseline: 1.1621x; 1.1621x over previous
//
#include <hip/hip_runtime.h>
#include <cstdint>
#include <cstddef>

// Problem constants
#define NTOK 2048      // B*S
#define DDIM 1024
#define FDIM 2048
#define NEXP 14
#define MAXT 2048      // max tokens per expert (one slot each)

#define BM 64          // m-tile (rows of gathered tokens)
#define BN 128         // n-tile
#define BK 32          // k-chunk
#define BSTR 34        // Bs row stride in shorts (pad 2 -> 4-way max on stores)

typedef __attribute__((ext_vector_type(8))) short short8;
typedef __attribute__((ext_vector_type(4))) float floatx4;

__device__ __forceinline__ unsigned short f2bf(float f) {
    unsigned u = __float_as_uint(f);
    unsigned r = u + 0x7fffu + ((u >> 16) & 1u);   // RNE
    return (unsigned short)(r >> 16);
}
__device__ __forceinline__ unsigned pack2bf(float lo, float hi) {
    return (unsigned)f2bf(lo) | ((unsigned)f2bf(hi) << 16);
}

// ---------------- zero: counters + accumulation buffer ----------------
__global__ __launch_bounds__(256) void zero_kernel(float* __restrict__ accb, int* __restrict__ cnt) {
    const size_t i = ((size_t)blockIdx.x * 256 + threadIdx.x) * 4;
    *(float4*)(accb + i) = float4{0.f, 0.f, 0.f, 0.f};
    if (blockIdx.x == 0 && threadIdx.x < NEXP) cnt[threadIdx.x] = 0;
}

// ---------------- gating: one wave per token ----------------
__global__ __launch_bounds__(256) void gate_kernel(
    const float* __restrict__ x, const float* __restrict__ gw,
    int* __restrict__ cnt, int* __restrict__ lists, float* __restrict__ wt)
{
    const int wave = threadIdx.x >> 6, lane = threadIdx.x & 63;
    const int n = blockIdx.x * 4 + wave;
    float part[NEXP];
#pragma unroll
    for (int e = 0; e < NEXP; ++e) part[e] = 0.f;
    const float* xr = x + (size_t)n * DDIM;
#pragma unroll 4
    for (int kk = 0; kk < DDIM / 64; ++kk) {
        const int d = kk * 64 + lane;
        const float xv = xr[d];
#pragma unroll
        for (int e = 0; e < NEXP; ++e)
            part[e] = fmaf(xv, gw[e * DDIM + d], part[e]);
    }
#pragma unroll
    for (int e = 0; e < NEXP; ++e) {
        float v = part[e];
        for (int off = 32; off; off >>= 1) v += __shfl_xor(v, off);
        part[e] = v;
    }
    int i0 = 0; float l0 = part[0];
#pragma unroll
    for (int e = 1; e < NEXP; ++e) if (part[e] > l0) { l0 = part[e]; i0 = e; }
    int i1 = -1; float l1 = -3.0e38f;
#pragma unroll
    for (int e = 0; e < NEXP; ++e) if (e != i0 && part[e] > l1) { l1 = part[e]; i1 = e; }
    if (lane == 0) {
        const float r  = __expf(l1 - l0);
        const float w0 = 1.f / (1.f + r);
        const float w1v = r / (1.f + r);
        wt[2 * n]     = w0;
        wt[2 * n + 1] = w1v;
        int p0 = atomicAdd(&cnt[i0], 1); lists[i0 * MAXT + p0] = 2 * n;
        int p1 = atomicAdd(&cnt[i1], 1); lists[i1 * MAXT + p1] = 2 * n + 1;
    }
}

// ---------------- GEMM1: hh[p][F] = gelu(x[tok] @ w1[e] + b1[e]) ----------------
// 64x128 tile, BK=32, 4 waves each 64m x 32n (acc 4x2), register prefetch.
__global__ __launch_bounds__(256) void gemm1_kernel(
    const float* __restrict__ x, const float* __restrict__ w1,
    const float* __restrict__ b1, const int* __restrict__ cnt,
    const int* __restrict__ lists, unsigned short* __restrict__ hh)
{
    const int e = blockIdx.z, mt = blockIdx.y, nt = blockIdx.x;
    const int count = cnt[e];
    if (mt * BM >= count) return;
    const int* list = lists + e * MAXT + mt * BM;
    const int mloc = min(BM, count - mt * BM);

    __shared__ __align__(16) unsigned short As[BM * BK];       // 4 KB, stride 32
    __shared__ __align__(16) unsigned short Bs[BN * BSTR];     // 8704 B

    const int t = threadIdx.x;
    const int lane = t & 63, wave = t >> 6;
    const int wn = wave * 32;
    const int lrow = lane & 15, lquad = lane >> 4;

    // A staging: 4 threads/row, 8 floats each
    const int arow = t >> 2, acol = (t & 3) * 8;
    const int tokA = list[arow < mloc ? arow : 0] >> 1;
    const float* aSrc = x + (size_t)tokA * DDIM + acol;
    // B staging: thread -> k-pair kp (2 rows), 8 n's
    const int kp = t >> 4, nb = (t & 15) * 8;
    const float* bSrc = w1 + (size_t)e * DDIM * FDIM + (size_t)(2 * kp) * FDIM + nt * BN + nb;

    floatx4 acc[4][2];
#pragma unroll
    for (int i = 0; i < 4; ++i)
#pragma unroll
        for (int j = 0; j < 2; ++j) acc[i][j] = (floatx4)0.f;

    // prefetch registers
    float4 pa0 = *(const float4*)(aSrc);
    float4 pa1 = *(const float4*)(aSrc + 4);
    float4 pb00 = *(const float4*)(bSrc);
    float4 pb01 = *(const float4*)(bSrc + 4);
    float4 pb10 = *(const float4*)(bSrc + FDIM);
    float4 pb11 = *(const float4*)(bSrc + FDIM + 4);

    for (int k0 = 0; k0 < DDIM; k0 += BK) {
        // store staged tile from registers
        {
            union { short8 v; unsigned short s[8]; } pk;
            pk.s[0]=f2bf(pa0.x); pk.s[1]=f2bf(pa0.y); pk.s[2]=f2bf(pa0.z); pk.s[3]=f2bf(pa0.w);
            pk.s[4]=f2bf(pa1.x); pk.s[5]=f2bf(pa1.y); pk.s[6]=f2bf(pa1.z); pk.s[7]=f2bf(pa1.w);
            *(short8*)(As + arow * BK + acol) = pk.v;
            float r0[8] = { pb00.x,pb00.y,pb00.z,pb00.w, pb01.x,pb01.y,pb01.z,pb01.w };
            float r1[8] = { pb10.x,pb10.y,pb10.z,pb10.w, pb11.x,pb11.y,pb11.z,pb11.w };
            unsigned* bs32 = (unsigned*)Bs;
#pragma unroll
            for (int i = 0; i < 8; ++i)
                bs32[((nb + i) * BSTR + 2 * kp) >> 1] = pack2bf(r0[i], r1[i]);
        }
        __syncthreads();
        if (k0 + BK < DDIM) {   // prefetch next
            pa0 = *(const float4*)(aSrc + k0 + BK);
            pa1 = *(const float4*)(aSrc + k0 + BK + 4);
            const float* bp = bSrc + (size_t)(k0 + BK) * FDIM;
            pb00 = *(const float4*)(bp);
            pb01 = *(const float4*)(bp + 4);
            pb10 = *(const float4*)(bp + FDIM);
            pb11 = *(const float4*)(bp + FDIM + 4);
        }
        short8 af[4], bfg[2];
#pragma unroll
        for (int i = 0; i < 4; ++i)
            af[i] = *(const short8*)(As + (i * 16 + lrow) * BK + lquad * 8);
#pragma unroll
        for (int j = 0; j < 2; ++j)
            bfg[j] = *(const short8*)(Bs + (wn + j * 16 + lrow) * BSTR + lquad * 8);
#pragma unroll
        for (int i = 0; i < 4; ++i)
#pragma unroll
            for (int j = 0; j < 2; ++j)
                acc[i][j] = __builtin_amdgcn_mfma_f32_16x16x32_bf16(af[i], bfg[j], acc[i][j], 0, 0, 0);
        __syncthreads();
    }
    // epilogue: bias + exact gelu, scatter rows to hh[pair][F]
#pragma unroll
    for (int j = 0; j < 2; ++j) {
        const int n = nt * BN + wn + j * 16 + lrow;
        const float bias = b1[e * FDIM + n];
#pragma unroll
        for (int i = 0; i < 4; ++i) {
            const int mbase = i * 16 + lquad * 4;
#pragma unroll
            for (int r = 0; r < 4; ++r) {
                const int m = mbase + r;
                if (m < mloc) {
                    const int p = list[m];
                    float v = acc[i][j][r] + bias;
                    v = 0.5f * v * (1.0f + erff(v * 0.70710678118654752f));
                    hh[(size_t)p * FDIM + n] = f2bf(v);
                }
            }
        }
    }
}

// ---------------- GEMM2: accb[tok][D] += wt[p] * (hh[p] @ w2[e] + b2[e]) ----------------
// K=2048 split into 2 chunks of 1024; fp32 atomicAdd into accb.
__global__ __launch_bounds__(256) void gemm2_kernel(
    const unsigned short* __restrict__ hh, const float* __restrict__ w2,
    const float* __restrict__ b2, const int* __restrict__ cnt,
    const int* __restrict__ lists, const float* __restrict__ wt,
    float* __restrict__ accb)
{
    const int e = blockIdx.z >> 1, ks = blockIdx.z & 1;
    const int mt = blockIdx.y, nt = blockIdx.x;
    const int count = cnt[e];
    if (mt * BM >= count) return;
    const int* list = lists + e * MAXT + mt * BM;
    const int mloc = min(BM, count - mt * BM);
    const int kbase = ks * (FDIM / 2);

    __shared__ __align__(16) unsigned short As[BM * BK];
    __shared__ __align__(16) unsigned short Bs[BN * BSTR];

    const int t = threadIdx.x;
    const int lane = t & 63, wave = t >> 6;
    const int wn = wave * 32;
    const int lrow = lane & 15, lquad = lane >> 4;

    const int arow = t >> 2, acol = (t & 3) * 8;
    const int pA = list[arow < mloc ? arow : 0];
    const unsigned short* aSrc = hh + (size_t)pA * FDIM + kbase + acol;
    const int kp = t >> 4, nb = (t & 15) * 8;
    const float* bSrc = w2 + (size_t)e * FDIM * DDIM + (size_t)(kbase + 2 * kp) * DDIM + nt * BN + nb;

    floatx4 acc[4][2];
#pragma unroll
    for (int i = 0; i < 4; ++i)
#pragma unroll
        for (int j = 0; j < 2; ++j) acc[i][j] = (floatx4)0.f;

    short8 pa = *(const short8*)(aSrc);
    float4 pb00 = *(const float4*)(bSrc);
    float4 pb01 = *(const float4*)(bSrc + 4);
    float4 pb10 = *(const float4*)(bSrc + DDIM);
    float4 pb11 = *(const float4*)(bSrc + DDIM + 4);

    for (int k0 = 0; k0 < FDIM / 2; k0 += BK) {
        {
            *(short8*)(As + arow * BK + acol) = pa;
            float r0[8] = { pb00.x,pb00.y,pb00.z,pb00.w, pb01.x,pb01.y,pb01.z,pb01.w };
            float r1[8] = { pb10.x,pb10.y,pb10.z,pb10.w, pb11.x,pb11.y,pb11.z,pb11.w };
            unsigned* bs32 = (unsigned*)Bs;
#pragma unroll
            for (int i = 0; i < 8; ++i)
                bs32[((nb + i) * BSTR + 2 * kp) >> 1] = pack2bf(r0[i], r1[i]);
        }
        __syncthreads();
        if (k0 + BK < FDIM / 2) {
            pa = *(const short8*)(aSrc + k0 + BK);
            const float* bp = bSrc + (size_t)(k0 + BK) * DDIM;
            pb00 = *(const float4*)(bp);
            pb01 = *(const float4*)(bp + 4);
            pb10 = *(const float4*)(bp + DDIM);
            pb11 = *(const float4*)(bp + DDIM + 4);
        }
        short8 af[4], bfg[2];
#pragma unroll
        for (int i = 0; i < 4; ++i)
            af[i] = *(const short8*)(As + (i * 16 + lrow) * BK + lquad * 8);
#pragma unroll
        for (int j = 0; j < 2; ++j)
            bfg[j] = *(const short8*)(Bs + (wn + j * 16 + lrow) * BSTR + lquad * 8);
#pragma unroll
        for (int i = 0; i < 4; ++i)
#pragma unroll
            for (int j = 0; j < 2; ++j)
                acc[i][j] = __builtin_amdgcn_mfma_f32_16x16x32_bf16(af[i], bfg[j], acc[i][j], 0, 0, 0);
        __syncthreads();
    }
#pragma unroll
    for (int j = 0; j < 2; ++j) {
        const int n = nt * BN + wn + j * 16 + lrow;
        const float bias = (ks == 0) ? b2[e * DDIM + n] : 0.f;
#pragma unroll
        for (int i = 0; i < 4; ++i) {
            const int mbase = i * 16 + lquad * 4;
#pragma unroll
            for (int r = 0; r < 4; ++r) {
                const int m = mbase + r;
                if (m < mloc) {
                    const int p = list[m];
                    const int tok = p >> 1;
                    const float v = (acc[i][j][r] + bias) * wt[p];
                    atomicAdd(&accb[(size_t)tok * DDIM + n], v);
                }
            }
        }
    }
}

// ---------------- finalize: out = clip(x + accb) ----------------
__global__ __launch_bounds__(256) void finalize_kernel(
    const float* __restrict__ x, const float* __restrict__ accb,
    float* __restrict__ out)
{
    const size_t i = ((size_t)blockIdx.x * 256 + threadIdx.x) * 4;
    float4 xv = *(const float4*)(x + i);
    float4 a  = *(const float4*)(accb + i);
    float4 r;
    r.x = fminf(fmaxf(xv.x + a.x, -100.f), 100.f);
    r.y = fminf(fmaxf(xv.y + a.y, -100.f), 100.f);
    r.z = fminf(fmaxf(xv.z + a.z, -100.f), 100.f);
    r.w = fminf(fmaxf(xv.w + a.w, -100.f), 100.f);
    *(float4*)(out + i) = r;
}

extern "C" void kernel_launch(void* const* d_in, const int* in_sizes, int n_in,
                              void* d_out, int out_size, void* d_ws, size_t ws_size,
                              hipStream_t stream) {
    const float* h  = (const float*)d_in[0];
    const float* gw = (const float*)d_in[1];
    const float* w1 = (const float*)d_in[2];
    const float* b1 = (const float*)d_in[3];
    const float* w2 = (const float*)d_in[4];
    const float* b2 = (const float*)d_in[5];
    float* out = (float*)d_out;

    // workspace layout
    char* ws = (char*)d_ws;
    int*   cnt   = (int*)ws;                                   // 256 B reserved
    int*   lists = (int*)(ws + 256);                           // 14*2048*4 = 114688
    float* wt    = (float*)(ws + 256 + 114688);                // 4096*4 = 16384
    float* accb  = (float*)(ws + 131328);                      // 2048*1024*4 = 8 MB
    unsigned short* hh = (unsigned short*)(ws + 131328 + 8388608); // 4096*2048*2 = 16 MB
    // total ws use: ~25.3 MB

    zero_kernel<<<NTOK * DDIM / (256 * 4), 256, 0, stream>>>(accb, cnt);
    gate_kernel<<<NTOK / 4, 256, 0, stream>>>(h, gw, cnt, lists, wt);
    gemm1_kernel<<<dim3(FDIM / BN, MAXT / BM, NEXP), 256, 0, stream>>>(h, w1, b1, cnt, lists, hh);
    gemm2_kernel<<<dim3(DDIM / BN, MAXT / BM, NEXP * 2), 256, 0, stream>>>(hh, w2, b2, cnt, lists, wt, accb);
    finalize_kernel<<<NTOK * DDIM / (256 * 4), 256, 0, stream>>>(h, accb, out);
}

// Round 3
// 433.668 us; speedup vs baseline: 1.3294x; 1.1440x over previous
//
#include <hip/hip_runtime.h>
#include <cstdint>
#include <cstddef>

// Problem constants
#define NTOK 2048      // B*S
#define DDIM 1024
#define FDIM 2048
#define NEXP 14
#define MAXT 2048

typedef __attribute__((ext_vector_type(8))) short short8;
typedef __attribute__((ext_vector_type(4))) float floatx4;

__device__ __forceinline__ unsigned pack2bf(float lo, float hi) {
    unsigned a = __float_as_uint(lo), b = __float_as_uint(hi);
    return ((a + 0x8000u) >> 16) | ((b + 0x8000u) & 0xffff0000u);
}
__device__ __forceinline__ unsigned short f2bf1(float f) {
    return (unsigned short)((__float_as_uint(f) + 0x8000u) >> 16);
}

// async global->LDS, 16B per lane; lds base must be wave-uniform
__device__ __forceinline__ void glds16(const void* g, void* lds) {
    __builtin_amdgcn_global_load_lds((const __attribute__((address_space(1))) unsigned*)g,
                                     (__attribute__((address_space(3))) unsigned*)lds, 16, 0, 0);
}

// ---------------- convert x -> bf16, zero counters ----------------
__global__ __launch_bounds__(256) void cvtx_kernel(const float* __restrict__ x,
                                                   unsigned short* __restrict__ xb,
                                                   int* __restrict__ cnt) {
    if (blockIdx.x == 0 && threadIdx.x < NEXP) cnt[threadIdx.x] = 0;
    const size_t i = ((size_t)blockIdx.x * 256 + threadIdx.x) * 8;
    float4 a = *(const float4*)(x + i);
    float4 b = *(const float4*)(x + i + 4);
    uint4 u;
    u.x = pack2bf(a.x, a.y); u.y = pack2bf(a.z, a.w);
    u.z = pack2bf(b.x, b.y); u.w = pack2bf(b.z, b.w);
    *(uint4*)(xb + i) = u;
}

// ---------------- gating: one wave per token ----------------
__global__ __launch_bounds__(256) void gate_kernel(
    const float* __restrict__ x, const float* __restrict__ gw,
    int* __restrict__ cnt, int* __restrict__ lists, float* __restrict__ wt)
{
    const int wave = threadIdx.x >> 6, lane = threadIdx.x & 63;
    const int n = blockIdx.x * 4 + wave;
    float part[NEXP];
#pragma unroll
    for (int e = 0; e < NEXP; ++e) part[e] = 0.f;
    const float4* xr = (const float4*)(x + (size_t)n * DDIM);
#pragma unroll
    for (int kk = 0; kk < 4; ++kk) {
        const float4 xv = xr[kk * 64 + lane];
#pragma unroll
        for (int e = 0; e < NEXP; ++e) {
            const float4 g = ((const float4*)(gw + e * DDIM))[kk * 64 + lane];
            part[e] = fmaf(xv.x, g.x, fmaf(xv.y, g.y, fmaf(xv.z, g.z, fmaf(xv.w, g.w, part[e]))));
        }
    }
#pragma unroll
    for (int e = 0; e < NEXP; ++e) {
        float v = part[e];
        for (int off = 32; off; off >>= 1) v += __shfl_xor(v, off);
        part[e] = v;
    }
    int i0 = 0; float l0 = part[0];
#pragma unroll
    for (int e = 1; e < NEXP; ++e) if (part[e] > l0) { l0 = part[e]; i0 = e; }
    int i1 = -1; float l1 = -3.0e38f;
#pragma unroll
    for (int e = 0; e < NEXP; ++e) if (e != i0 && part[e] > l1) { l1 = part[e]; i1 = e; }
    if (lane == 0) {
        const float r  = __expf(l1 - l0);
        wt[2 * n]     = 1.f / (1.f + r);
        wt[2 * n + 1] = r / (1.f + r);
        int p0 = atomicAdd(&cnt[i0], 1); lists[i0 * MAXT + p0] = 2 * n;
        int p1 = atomicAdd(&cnt[i1], 1); lists[i1 * MAXT + p1] = 2 * n + 1;
    }
}

// ---------------- build compact (expert, m-tile) job list ----------------
#define MAXJOBS 78
__global__ void jobs_kernel(const int* __restrict__ cnt, int* __restrict__ job_e,
                            int* __restrict__ job_mt, int* __restrict__ njobs) {
    if (threadIdx.x == 0) {
        int J = 0;
        for (int e = 0; e < NEXP; ++e) {
            const int m = (cnt[e] + 63) >> 6;
            for (int i = 0; i < m; ++i) { job_e[J] = e; job_mt[J] = i; ++J; }
        }
        njobs[0] = J;
    }
}

// ---------------- GEMM1: hh[p][F] = gelu(xb[tok] @ w1[e] + b1[e]) ----------------
// BM=64, BN=128, BK=32, double-buffered LDS, single barrier/iter.
__global__ __launch_bounds__(256) void gemm1_kernel(
    const unsigned short* __restrict__ xb, const float* __restrict__ w1,
    const float* __restrict__ b1, const int* __restrict__ cnt,
    const int* __restrict__ lists, const int* __restrict__ job_e,
    const int* __restrict__ job_mt, const int* __restrict__ njobs,
    unsigned short* __restrict__ hh)
{
    const int j = blockIdx.y;
    if (j >= njobs[0]) return;
    const int e = job_e[j], mt = job_mt[j], nt = blockIdx.x;
    const int count = cnt[e];
    const int* list = lists + e * MAXT + mt * 64;
    const int mloc = min(64, count - mt * 64);

    __shared__ __align__(16) unsigned short As[2][64 * 32];    // 8 KB
    __shared__ __align__(16) unsigned short Bs[2][128 * 32];   // 16 KB

    const int t = threadIdx.x, lane = t & 63, wave = t >> 6;
    const int lrow = lane & 15, lq = lane >> 4;
    const int wn = wave * 32;

    // A gather source: wave stages rows 16w..16w+15; lane -> (row = l>>2, kchunk = l&3)
    const int arow = wave * 16 + (lane >> 2);
    const int atok = list[min(arow, mloc - 1)] >> 1;
    const unsigned short* aG = xb + (size_t)atok * DDIM + (lane & 3) * 8;
    // B: thread -> n = t&127, chunk group bg = t>>7 (chunks bg, bg+2); 8 k-strided dwords each
    const int bn = t & 127, bg = t >> 7;
    const float* bG = w1 + (size_t)e * DDIM * FDIM + nt * 128 + bn;

    floatx4 acc[4][2];
#pragma unroll
    for (int i = 0; i < 4; ++i)
#pragma unroll
        for (int jn = 0; jn < 2; ++jn) acc[i][jn] = (floatx4)0.f;

    float br[2][8];
    // ---- prologue: tile 0 into buf0, tile 1 into regs ----
    glds16(aG, &As[0][wave * 512]);
#pragma unroll
    for (int c = 0; c < 2; ++c) {
        const int kc = bg + 2 * c;
#pragma unroll
        for (int jj = 0; jj < 8; ++jj) br[c][jj] = bG[(size_t)(kc * 8 + jj) * FDIM];
    }
#pragma unroll
    for (int c = 0; c < 2; ++c) {
        const int kc = bg + 2 * c;
        uint4 u;
        u.x = pack2bf(br[c][0], br[c][1]); u.y = pack2bf(br[c][2], br[c][3]);
        u.z = pack2bf(br[c][4], br[c][5]); u.w = pack2bf(br[c][6], br[c][7]);
        *(uint4*)&Bs[0][bn * 32 + ((kc ^ (bn & 3)) * 8)] = u;
    }
#pragma unroll
    for (int c = 0; c < 2; ++c) {
        const int kc = bg + 2 * c;
#pragma unroll
        for (int jj = 0; jj < 8; ++jj) br[c][jj] = bG[(size_t)(32 + kc * 8 + jj) * FDIM];
    }

    int p = 0;
    for (int k0 = 0; k0 < DDIM; k0 += 32) {
        __syncthreads();
        if (k0 + 32 < DDIM) {
            glds16(aG + k0 + 32, &As[p ^ 1][wave * 512]);
#pragma unroll
            for (int c = 0; c < 2; ++c) {
                const int kc = bg + 2 * c;
                uint4 u;
                u.x = pack2bf(br[c][0], br[c][1]); u.y = pack2bf(br[c][2], br[c][3]);
                u.z = pack2bf(br[c][4], br[c][5]); u.w = pack2bf(br[c][6], br[c][7]);
                *(uint4*)&Bs[p ^ 1][bn * 32 + ((kc ^ (bn & 3)) * 8)] = u;
            }
        }
        if (k0 + 64 < DDIM) {
#pragma unroll
            for (int c = 0; c < 2; ++c) {
                const int kc = bg + 2 * c;
#pragma unroll
                for (int jj = 0; jj < 8; ++jj) br[c][jj] = bG[(size_t)(k0 + 64 + kc * 8 + jj) * FDIM];
            }
        }
        short8 af[4], bf[2];
#pragma unroll
        for (int i = 0; i < 4; ++i)
            af[i] = *(const short8*)&As[p][(i * 16 + lrow) * 32 + lq * 8];
#pragma unroll
        for (int jn = 0; jn < 2; ++jn) {
            const int n = wn + jn * 16 + lrow;
            bf[jn] = *(const short8*)&Bs[p][n * 32 + ((lq ^ (n & 3)) * 8)];
        }
#pragma unroll
        for (int i = 0; i < 4; ++i)
#pragma unroll
            for (int jn = 0; jn < 2; ++jn)
                acc[i][jn] = __builtin_amdgcn_mfma_f32_16x16x32_bf16(af[i], bf[jn], acc[i][jn], 0, 0, 0);
        p ^= 1;
    }
    // epilogue: bias + exact gelu -> hh (bf16)
#pragma unroll
    for (int jn = 0; jn < 2; ++jn) {
        const int n = nt * 128 + wn + jn * 16 + lrow;
        const float bias = b1[e * FDIM + n];
#pragma unroll
        for (int i = 0; i < 4; ++i) {
#pragma unroll
            for (int r = 0; r < 4; ++r) {
                const int m = i * 16 + lq * 4 + r;
                if (m < mloc) {
                    const int pp = list[m];
                    float v = acc[i][jn][r] + bias;
                    v = 0.5f * v * (1.0f + erff(v * 0.70710678118654752f));
                    hh[(size_t)pp * FDIM + n] = f2bf1(v);
                }
            }
        }
    }
}

// ---------------- GEMM2: out_slot[tok][D] = wt[p] * (hh[p] @ w2[e] + b2[e]) ----------------
// BM=64, BN=64, BK=32, dbuf, direct stores (no atomics).
__global__ __launch_bounds__(256) void gemm2_kernel(
    const unsigned short* __restrict__ hh, const float* __restrict__ w2,
    const float* __restrict__ b2, const int* __restrict__ cnt,
    const int* __restrict__ lists, const int* __restrict__ job_e,
    const int* __restrict__ job_mt, const int* __restrict__ njobs,
    const float* __restrict__ wt, float* __restrict__ out0, float* __restrict__ out1)
{
    const int j = blockIdx.y;
    if (j >= njobs[0]) return;
    const int e = job_e[j], mt = job_mt[j], nt = blockIdx.x;
    const int count = cnt[e];
    const int* list = lists + e * MAXT + mt * 64;
    const int mloc = min(64, count - mt * 64);

    __shared__ __align__(16) unsigned short As[2][64 * 32];   // 8 KB
    __shared__ __align__(16) unsigned short Bs[2][64 * 32];   // 8 KB

    const int t = threadIdx.x, lane = t & 63, wave = t >> 6;
    const int lrow = lane & 15, lq = lane >> 4;
    const int wm = (wave & 1) * 32, wn = (wave >> 1) * 16;

    const int arow = wave * 16 + (lane >> 2);
    const int apair = list[min(arow, mloc - 1)];
    const unsigned short* aG = hh + (size_t)apair * FDIM + (lane & 3) * 8;
    // B: thread -> n = t&63, chunk kc = t>>6 (0..3)
    const int bn = t & 63, bkc = t >> 6;
    const float* bG = w2 + (size_t)e * FDIM * DDIM + nt * 64 + bn;

    floatx4 acc[2][2];
#pragma unroll
    for (int i = 0; i < 2; ++i)
#pragma unroll
        for (int jn = 0; jn < 2; ++jn) acc[i][jn] = (floatx4)0.f;

    float br[8];
    glds16(aG, &As[0][wave * 512]);
#pragma unroll
    for (int jj = 0; jj < 8; ++jj) br[jj] = bG[(size_t)(bkc * 8 + jj) * DDIM];
    {
        uint4 u;
        u.x = pack2bf(br[0], br[1]); u.y = pack2bf(br[2], br[3]);
        u.z = pack2bf(br[4], br[5]); u.w = pack2bf(br[6], br[7]);
        *(uint4*)&Bs[0][bn * 32 + ((bkc ^ (bn & 3)) * 8)] = u;
    }
#pragma unroll
    for (int jj = 0; jj < 8; ++jj) br[jj] = bG[(size_t)(32 + bkc * 8 + jj) * DDIM];

    int p = 0;
    for (int k0 = 0; k0 < FDIM; k0 += 32) {
        __syncthreads();
        if (k0 + 32 < FDIM) {
            glds16(aG + k0 + 32, &As[p ^ 1][wave * 512]);
            uint4 u;
            u.x = pack2bf(br[0], br[1]); u.y = pack2bf(br[2], br[3]);
            u.z = pack2bf(br[4], br[5]); u.w = pack2bf(br[6], br[7]);
            *(uint4*)&Bs[p ^ 1][bn * 32 + ((bkc ^ (bn & 3)) * 8)] = u;
        }
        if (k0 + 64 < FDIM) {
#pragma unroll
            for (int jj = 0; jj < 8; ++jj) br[jj] = bG[(size_t)(k0 + 64 + bkc * 8 + jj) * DDIM];
        }
        short8 af[2], bf[2];
#pragma unroll
        for (int i = 0; i < 2; ++i)
            af[i] = *(const short8*)&As[p][(wm + i * 16 + lrow) * 32 + lq * 8];
#pragma unroll
        for (int jn = 0; jn < 2; ++jn) {
            const int n = wn + jn * 16 + lrow;   // wait: wn span is 16, jn*16 exceeds — fixed below
            bf[jn] = *(const short8*)&Bs[p][((wn * 2) + jn * 16 + lrow) * 32 + ((lq ^ (((wn * 2) + jn * 16 + lrow) & 3)) * 8)];
        }
#pragma unroll
        for (int i = 0; i < 2; ++i)
#pragma unroll
            for (int jn = 0; jn < 2; ++jn)
                acc[i][jn] = __builtin_amdgcn_mfma_f32_16x16x32_bf16(af[i], bf[jn], acc[i][jn], 0, 0, 0);
        p ^= 1;
    }
#pragma unroll
    for (int jn = 0; jn < 2; ++jn) {
        const int n = nt * 64 + (wn * 2) + jn * 16 + lrow;
        const float bias = b2[e * DDIM + n];
#pragma unroll
        for (int i = 0; i < 2; ++i) {
#pragma unroll
            for (int r = 0; r < 4; ++r) {
                const int m = wm + i * 16 + lq * 4 + r;
                if (m < mloc) {
                    const int pp = list[m];
                    const int tok = pp >> 1;
                    const float v = (acc[i][jn][r] + bias) * wt[pp];
                    float* dst = (pp & 1) ? out1 : out0;
                    dst[(size_t)tok * DDIM + n] = v;
                }
            }
        }
    }
}

// ---------------- finalize: out = clip(x + out0 + out1) ----------------
__global__ __launch_bounds__(256) void finalize_kernel(
    const float* __restrict__ x, const float* __restrict__ o1,
    float* __restrict__ out)   // out currently holds out0
{
    const size_t i = ((size_t)blockIdx.x * 256 + threadIdx.x) * 4;
    float4 xv = *(const float4*)(x + i);
    float4 a  = *(const float4*)(out + i);
    float4 b  = *(const float4*)(o1 + i);
    float4 r;
    r.x = fminf(fmaxf(xv.x + a.x + b.x, -100.f), 100.f);
    r.y = fminf(fmaxf(xv.y + a.y + b.y, -100.f), 100.f);
    r.z = fminf(fmaxf(xv.z + a.z + b.z, -100.f), 100.f);
    r.w = fminf(fmaxf(xv.w + a.w + b.w, -100.f), 100.f);
    *(float4*)(out + i) = r;
}

extern "C" void kernel_launch(void* const* d_in, const int* in_sizes, int n_in,
                              void* d_out, int out_size, void* d_ws, size_t ws_size,
                              hipStream_t stream) {
    const float* h  = (const float*)d_in[0];
    const float* gw = (const float*)d_in[1];
    const float* w1 = (const float*)d_in[2];
    const float* b1 = (const float*)d_in[3];
    const float* w2 = (const float*)d_in[4];
    const float* b2 = (const float*)d_in[5];
    float* out = (float*)d_out;

    // workspace layout (bytes)
    char* ws = (char*)d_ws;
    int*   cnt    = (int*)ws;                         // 256
    int*   lists  = (int*)(ws + 256);                 // 114688
    float* wt     = (float*)(ws + 114944);            // 16384 -> 131328
    int*   job_e  = (int*)(ws + 131328);              // 512
    int*   job_mt = (int*)(ws + 131840);              // 512
    int*   njobs  = (int*)(ws + 132352);              // 256 -> 132608
    unsigned short* xb = (unsigned short*)(ws + 262144);            // 4 MB
    float* o1     = (float*)(ws + 262144 + 4194304);                // 8 MB
    unsigned short* hhb = (unsigned short*)(ws + 262144 + 4194304 + 8388608); // 16 MB
    // total ~28.3 MB

    cvtx_kernel<<<NTOK * DDIM / (256 * 8), 256, 0, stream>>>(h, xb, cnt);
    gate_kernel<<<NTOK / 4, 256, 0, stream>>>(h, gw, cnt, lists, wt);
    jobs_kernel<<<1, 64, 0, stream>>>(cnt, job_e, job_mt, njobs);
    gemm1_kernel<<<dim3(FDIM / 128, MAXJOBS), 256, 0, stream>>>(xb, w1, b1, cnt, lists, job_e, job_mt, njobs, hhb);
    gemm2_kernel<<<dim3(DDIM / 64, MAXJOBS), 256, 0, stream>>>(hhb, w2, b2, cnt, lists, job_e, job_mt, njobs, wt, out, o1);
    finalize_kernel<<<NTOK * DDIM / (256 * 4), 256, 0, stream>>>(h, o1, out);
}